// Round 8
// baseline (139.249 us; speedup 1.0000x reference)
//
#include <hip/hip_runtime.h>
#include <hip/hip_bf16.h>

// NeighbourhoodAttnBlock: B=2, H=W=64, D=512, NH=8, DH=64, KERNEL=7
// Inputs fp32; output fp32. Internal pipeline bf16 MFMA.
// Stage 0: fused convert x, w_qkv, w_out fp32 -> bf16 in ws
// Stage 1: qkv GEMM (LDS-staged) -> q,k [bh][s][dh]; vt [bh][dh][s]
// Stage 2: barrier-free single-wave attention: one wave per (bh, 2x8 strip),
//          per-wave 8x16 key window staged in wave-private LDS
// Stage 3: out GEMM (LDS-staged, BN=64) -> d_out (fp32)

typedef __bf16 bf16x8 __attribute__((ext_vector_type(8)));
typedef __bf16 bf16x4 __attribute__((ext_vector_type(4)));
typedef float  f32x4  __attribute__((ext_vector_type(4)));

__global__ __launch_bounds__(256) void cvt_all(
    const float* __restrict__ x, const float* __restrict__ wq,
    const float* __restrict__ wo, __bf16* __restrict__ xb,
    __bf16* __restrict__ wqb, __bf16* __restrict__ wob) {
  int i = blockIdx.x * 256 + threadIdx.x;  // 1310720 total f32x4 chunks
  const float* src;
  __bf16* dst;
  int j = i;
  if (j < 1048576) {
    src = x; dst = xb;
  } else if (j < 1048576 + 196608) {
    j -= 1048576; src = wq; dst = wqb;
  } else {
    j -= 1048576 + 196608; src = wo; dst = wob;
  }
  f32x4 v = ((const f32x4*)src)[j];
  bf16x4 o;
  o[0] = (__bf16)v[0]; o[1] = (__bf16)v[1];
  o[2] = (__bf16)v[2]; o[3] = (__bf16)v[3];
  ((bf16x4*)dst)[j] = o;
}

__device__ __forceinline__ void gload_lds16(const __bf16* g, __bf16* l) {
  __builtin_amdgcn_global_load_lds(
      (const __attribute__((address_space(1))) void*)g,
      (__attribute__((address_space(3))) void*)l, 16, 0, 0);
}

// C[i][e] = sum_d A[i][d] * W[e][d];  A:[M,512], W:[E,512] row-major bf16.
// 128xBN block tile, 4 waves x (64 x BN/2), BK=32, global_load_lds staging.
template <bool QKV, int BN>
__global__ __launch_bounds__(256, 3) void gemm_lds(
    const __bf16* __restrict__ A, const __bf16* __restrict__ W,
    __bf16* __restrict__ qo, __bf16* __restrict__ ko, __bf16* __restrict__ vo,
    float* __restrict__ co, int etiles) {
  constexpr int K = 512;
  constexpr int NT = BN / 32;
  __shared__ alignas(16) __bf16 Al[128 * 32];
  __shared__ alignas(16) __bf16 Wl[BN * 32];
  const int tid = threadIdx.x;
  const int wv = tid >> 6, lane = tid & 63;
  const int n16 = lane & 15, quad = lane >> 4;
  const int bi = blockIdx.x / etiles, be = blockIdx.x % etiles;
  const int i0 = bi << 7, e0 = be * BN;
  const int wm = (wv & 1) << 6, we = (wv >> 1) * (BN / 2);

  const int srow = (wv << 4) + (lane >> 2);
  const int scol = (lane & 3) << 3;
  const __bf16* gA = A + (size_t)(i0 + srow) * K + scol;
  const __bf16* gW = W + (size_t)(e0 + srow) * K + scol;
  __bf16* lA = &Al[(wv << 9) + (lane << 3)];
  __bf16* lW = &Wl[(wv << 9) + (lane << 3)];

  f32x4 acc[4][NT];
#pragma unroll
  for (int a = 0; a < 4; ++a)
#pragma unroll
    for (int b = 0; b < NT; ++b) acc[a][b] = (f32x4){0.f, 0.f, 0.f, 0.f};

  for (int k0 = 0; k0 < K; k0 += 32) {
    if (k0) __syncthreads();
    gload_lds16(gA + k0, lA);
    gload_lds16(gA + (size_t)64 * K + k0, lA + 64 * 32);
    gload_lds16(gW + k0, lW);
    if (BN == 128) gload_lds16(gW + (size_t)64 * K + k0, lW + 64 * 32);
    __syncthreads();

    bf16x8 af[4], wf[NT];
#pragma unroll
    for (int t = 0; t < 4; ++t)
      af[t] = *(const bf16x8*)&Al[(wm + t * 16 + n16) * 32 + quad * 8];
#pragma unroll
    for (int t = 0; t < NT; ++t)
      wf[t] = *(const bf16x8*)&Wl[(we + t * 16 + n16) * 32 + quad * 8];
#pragma unroll
    for (int mt = 0; mt < 4; ++mt)
#pragma unroll
      for (int nt = 0; nt < NT; ++nt)
        acc[mt][nt] = __builtin_amdgcn_mfma_f32_16x16x32_bf16(
            af[mt], wf[nt], acc[mt][nt], 0, 0, 0);
  }

#pragma unroll
  for (int mt = 0; mt < 4; ++mt)
#pragma unroll
    for (int nt = 0; nt < NT; ++nt) {
      f32x4 f = acc[mt][nt];
      int e = e0 + we + nt * 16 + n16;
#pragma unroll
      for (int rg = 0; rg < 4; ++rg) {
        int i = i0 + wm + mt * 16 + quad * 4 + rg;
        float val = f[rg];
        if (QKV) {
          int t = e >> 9, head = (e >> 6) & 7, dh = e & 63;
          int b = i >> 12, s = i & 4095;
          int bh = b * 8 + head;
          if (t == 2) {
            vo[((size_t)bh * 64 + dh) * 4096 + s] = (__bf16)val;  // vt[bh][dh][s]
          } else {
            size_t off = (((size_t)bh * 4096) + s) * 64 + dh;
            ((t == 0) ? qo : ko)[off] = (__bf16)val;
          }
        } else {
          co[(size_t)i * 512 + e] = val;  // fp32 output
        }
      }
    }
}

// Barrier-free single-wave neighbourhood attention.
// One 64-thread block (one wave) per (bh, 2-row x 8-col query strip).
// Window: 8 rows x 16 cols = 128 keys, wave-private in LDS.
// kv[]: K window [key(kr*16+kc)][dh] (16 KB), then overlaid by
//       V window [dh][136 (128 keys + 8 pad)] (17 KB) after lgkmcnt(0).
// P: per-wave [16 q][136] bf16.
__global__ __launch_bounds__(64) void attn_wave(
    const __bf16* __restrict__ q, const __bf16* __restrict__ k,
    const __bf16* __restrict__ vt, __bf16* __restrict__ out) {
  __shared__ alignas(16) __bf16 kv[8704];   // max(8192 K, 8704 V padded)
  __shared__ alignas(16) __bf16 P[16 * 136];
  const int lane = threadIdx.x;
  const int n16 = lane & 15, quad = lane >> 4;
  const int bh = blockIdx.x >> 8;
  const int strip = blockIdx.x & 255;
  const int qh0 = (strip >> 3) << 1, qw0 = (strip & 7) << 3;
  int wh0 = qh0 - 3; wh0 = wh0 < 0 ? 0 : (wh0 > 56 ? 56 : wh0);
  int wc0 = qw0 - 3; wc0 = wc0 < 0 ? 0 : (wc0 > 48 ? 48 : wc0);
  wc0 &= ~1;  // -> multiple of 4; 16-col window covers [qw0-3, qw0+10]
  const size_t base = (size_t)bh * 4096 * 64;

  // ---- Q A-frags: 16 queries (2 rows x 8 cols), lane n16 = query ----
  const int sqa = (qh0 + (n16 >> 3)) * 64 + qw0 + (n16 & 7);
  const __bf16* qp = q + base + (size_t)sqa * 64 + quad * 8;
  bf16x8 aq0 = *(const bf16x8*)qp;
  bf16x8 aq1 = *(const bf16x8*)(qp + 32);

  // ---- coop load K window: 8 rows x 2 KB, 16 b128 chunks per lane ----
  const __bf16* kbase = k + base;
#pragma unroll
  for (int i = 0; i < 16; ++i) {
    int ch = i * 64 + lane;           // 1024 chunks
    int kr = ch >> 7, wi = ch & 127;  // 128 chunks per key-row
    int kc = wi >> 3, dh8 = wi & 7;
    bf16x8 d = *(const bf16x8*)(kbase +
        (size_t)((wh0 + kr) * 64 + wc0 + kc) * 64 + dh8 * 8);
    *(bf16x8*)&kv[(kr * 16 + kc) * 64 + dh8 * 8] = d;
  }

  // ---- QK^T: S[nt] over 8 window rows (LDS reads ordered after writes
  //      by the per-wave in-order LDS pipe + compiler alias analysis) ----
  f32x4 S[8];
  const int skw = wc0 + n16;
#pragma unroll
  for (int nt = 0; nt < 8; ++nt) {
    int key = nt * 16 + n16;
    bf16x8 b0 = *(const bf16x8*)&kv[key * 64 + quad * 8];
    bf16x8 b1 = *(const bf16x8*)&kv[key * 64 + 32 + quad * 8];
    f32x4 s = {0.f, 0.f, 0.f, 0.f};
    s = __builtin_amdgcn_mfma_f32_16x16x32_bf16(aq0, b0, s, 0, 0, 0);
    s = __builtin_amdgcn_mfma_f32_16x16x32_bf16(aq1, b1, s, 0, 0, 0);
    S[nt] = s;
  }

  // ---- exact mask + scale + row max (rows live in 16-lane groups) ----
  float mx[4] = {-1e30f, -1e30f, -1e30f, -1e30f};
#pragma unroll
  for (int reg = 0; reg < 4; ++reg) {
    int qi = quad * 4 + reg;
    int qh = qh0 + (qi >> 3), qw = qw0 + (qi & 7);
    int sh = qh - 3; sh = sh < 0 ? 0 : (sh > 57 ? 57 : sh);
    int sw = qw - 3; sw = sw < 0 ? 0 : (sw > 57 ? 57 : sw);
    bool wok = (skw >= sw) && (skw < sw + 7);
#pragma unroll
    for (int nt = 0; nt < 8; ++nt) {
      int kh = wh0 + nt;
      bool ok = wok && (kh >= sh) && (kh < sh + 7);
      float val = ok ? S[nt][reg] * 0.125f : -1e30f;
      S[nt][reg] = val;
      mx[reg] = mx[reg] > val ? mx[reg] : val;
    }
  }
#pragma unroll
  for (int reg = 0; reg < 4; ++reg)
#pragma unroll
    for (int off = 8; off >= 1; off >>= 1) {
      float o = __shfl_xor(mx[reg], off);
      mx[reg] = mx[reg] > o ? mx[reg] : o;
    }

  // ---- exp + row sum ----
  float sm[4] = {0.f, 0.f, 0.f, 0.f};
#pragma unroll
  for (int nt = 0; nt < 8; ++nt)
#pragma unroll
    for (int reg = 0; reg < 4; ++reg) {
      float p = __expf(S[nt][reg] - mx[reg]);
      S[nt][reg] = p;
      sm[reg] += p;
    }
#pragma unroll
  for (int reg = 0; reg < 4; ++reg)
#pragma unroll
    for (int off = 8; off >= 1; off >>= 1) sm[reg] += __shfl_xor(sm[reg], off);

  // ---- P -> LDS (C-layout scatter, rows padded to 136: conflict-light) ----
#pragma unroll
  for (int reg = 0; reg < 4; ++reg) {
    float inv = 1.f / sm[reg];
    int row = quad * 4 + reg;
#pragma unroll
    for (int nt = 0; nt < 8; ++nt)
      P[row * 136 + nt * 16 + n16] = (__bf16)(S[nt][reg] * inv);
  }

  // ---- drain LDS (K reads + P writes), then overlay V into kv ----
  asm volatile("s_waitcnt lgkmcnt(0)" ::: "memory");

  // V window: vwin[dh][136], 8-B chunks (wc0 is 4-elem aligned, not 8)
  const __bf16* vtb = vt + base;
#pragma unroll
  for (int i = 0; i < 32; ++i) {
    int c = i * 64 + lane;           // 2048 8-B chunks
    int dh = c >> 5, rem = c & 31;   // 32 chunks per dh: 8 rows x 4 quarters
    int kr = rem >> 2, qtr = rem & 3;
    bf16x4 d = *(const bf16x4*)(vtb + (size_t)dh * 4096 +
                                (wh0 + kr) * 64 + wc0 + qtr * 4);
    *(bf16x4*)&kv[dh * 136 + kr * 16 + qtr * 4] = d;
  }

  // ---- PV: O[16q x 64dh] = P(16x128) . V_win(128x64), all LDS ----
  f32x4 O[4] = {{0.f, 0.f, 0.f, 0.f},
                {0.f, 0.f, 0.f, 0.f},
                {0.f, 0.f, 0.f, 0.f},
                {0.f, 0.f, 0.f, 0.f}};
#pragma unroll
  for (int kt = 0; kt < 4; ++kt) {
    bf16x8 pa = *(const bf16x8*)&P[n16 * 136 + kt * 32 + quad * 8];
    int key0 = kt * 32 + quad * 8;
#pragma unroll
    for (int ntv = 0; ntv < 4; ++ntv) {
      bf16x8 vb = *(const bf16x8*)&kv[(ntv * 16 + n16) * 136 + key0];
      O[ntv] = __builtin_amdgcn_mfma_f32_16x16x32_bf16(pa, vb, O[ntv], 0, 0, 0);
    }
  }

  // ---- epilogue: ao[b][s][head*64+dh] bf16 ----
  const int b = bh >> 3, head = bh & 7;
#pragma unroll
  for (int ntv = 0; ntv < 4; ++ntv)
#pragma unroll
    for (int reg = 0; reg < 4; ++reg) {
      int qi = quad * 4 + reg;
      int s_q = (qh0 + (qi >> 3)) * 64 + qw0 + (qi & 7);
      int dh = ntv * 16 + n16;
      out[((size_t)(b * 4096 + s_q)) * 512 + head * 64 + dh] =
          (__bf16)O[ntv][reg];
    }
}

extern "C" void kernel_launch(void* const* d_in, const int* in_sizes, int n_in,
                              void* d_out, int out_size, void* d_ws,
                              size_t ws_size, hipStream_t stream) {
  const float* x = (const float*)d_in[0];      // [2,64,64,512] fp32
  const float* w_qkv = (const float*)d_in[1];  // [1536,512] fp32
  const float* w_out = (const float*)d_in[2];  // [512,512] fp32
  float* out = (float*)d_out;                  // [2,64,64,512] fp32

  const size_t qelems = (size_t)2 * 8 * 4096 * 64;  // 4,194,304
  __bf16* q = (__bf16*)d_ws;
  __bf16* k = q + qelems;
  __bf16* vt = k + qelems;          // V transposed [bh][dh][s]
  __bf16* xb = vt + qelems;         // converted x; reused as ao
  __bf16* wqb = xb + qelems;        // converted w_qkv
  __bf16* wob = wqb + 1536 * 512;   // converted w_out
  __bf16* ao = xb;                  // attn out aliases xb

  // Stage 0: fused fp32 -> bf16
  cvt_all<<<dim3(5120), dim3(256), 0, stream>>>(x, w_qkv, w_out, xb, wqb, wob);

  // Stage 1: QKV GEMM: 64 i-tiles x 12 e-tiles = 768 blocks (3/CU)
  gemm_lds<true, 128><<<dim3(768), dim3(256), 0, stream>>>(
      xb, wqb, q, k, vt, nullptr, 12);
  // Stage 2: attention: 16 bh x 256 strips = 4096 single-wave blocks
  attn_wave<<<dim3(4096), dim3(64), 0, stream>>>(q, k, vt, ao);
  // Stage 3: out GEMM: 64 i-tiles x 8 e-tiles = 512 blocks (2/CU)
  gemm_lds<false, 64><<<dim3(512), dim3(256), 0, stream>>>(
      ao, wob, nullptr, nullptr, nullptr, out, 8);
}